// Round 7
// baseline (682.674 us; speedup 1.0000x reference)
//
#include <hip/hip_runtime.h>
#include <stdint.h>
#include <stddef.h>

// ABI: all inputs fp32, output fp32. fp32 inputs pre-converted ONCE to bf16;
// both GEMMs run the proven global_load_lds-direct bf16 pipeline (m97
// structure, ~900 TF tier). 5 dispatches:
//   cvt2(x,wqkv) -> gemm1 -> postproc(prep + vtrans + wo-cvt) -> attn -> gemm2
// attn: UNPAIRED q-tiles (1024 blocks, longest-first) + V read direct from
// L2 (no sVT staging) -> LDS 40KB, 4 blocks/CU, 16 waves/CU
// (was 2 blocks/CU, 8 waves/CU, MfmaUtil 11% = latency-bound).
typedef __bf16 bf16_t;
typedef __bf16 bf16x8 __attribute__((ext_vector_type(8)));
typedef float  f32x4  __attribute__((ext_vector_type(4)));

#define T_SEQ 2048
#define NH    32
#define NKV   8
#define DH    128
#define HIDN  4096
#define NQKV  6144
#define SCALE 0.08838834764831845f
// Static softmax max-bound: RMSNorm(w=1) + RoPE give ||q||=||k||=sqrt(128)
// (up to bf16 eps), so s*SCALE <= 11.36 < 11.5. Constant shift cancels in
// p/sum(p); removes running-max/rescale entirely.
// exp2 folding: p = exp2(s*SCALE*log2e - MBOUND*log2e)
#define C1_EXP2 0.12751743187767f
#define C2_EXP2 16.590992970223f

__device__ inline float b2f(bf16_t v) {
  uint32_t u = ((uint32_t)__builtin_bit_cast(uint16_t, v)) << 16;
  return __builtin_bit_cast(float, u);
}
__device__ inline bf16_t f2b(float f) { return (bf16_t)f; }  // native RNE cvt
__device__ inline void gl_lds16(const void* g, void* l) {
  __builtin_amdgcn_global_load_lds(
      (__attribute__((address_space(1))) void*)g,
      (__attribute__((address_space(3))) void*)l, 16, 0, 0);
}
__device__ inline f32x4 mfma16(bf16x8 a, bf16x8 b, f32x4 c) {
  return __builtin_amdgcn_mfma_f32_16x16x32_bf16(a, b, c, 0, 0, 0);
}
__device__ inline void store_val(float* p, float v)  { *p = v; }
__device__ inline void store_val(bf16_t* p, float v) { *p = f2b(v); }

// ---------------------------------------------------------------------------
// cvt2: fp32 -> bf16 for two tensors in one dispatch (blocks [0,na) -> a,
// rest -> b). 8 elems/thread (32B load, 16B store).
// ---------------------------------------------------------------------------
__global__ __launch_bounds__(256)
void cvt2_kernel(const float* __restrict__ a, bf16_t* __restrict__ ao, int na,
                 const float* __restrict__ b, bf16_t* __restrict__ bo) {
  int blk = blockIdx.x;
  const float* in;
  bf16_t* out;
  int rb;
  if (blk < na) { in = a; out = ao; rb = blk; }
  else          { in = b; out = bo; rb = blk - na; }
  size_t i = ((size_t)rb * 256 + threadIdx.x) * 8;
  f32x4 va = *(const f32x4*)(in + i);
  f32x4 vb = *(const f32x4*)(in + i + 4);
  bf16x8 o;
#pragma unroll
  for (int e = 0; e < 4; ++e) { o[e] = f2b(va[e]); o[e + 4] = f2b(vb[e]); }
  *(bf16x8*)(out + i) = o;
}

// ---------------------------------------------------------------------------
// GEMM: C[M,N] = A[M,K] * Bw[N,K]^T (+ bias[N]).  A,Bw bf16 K-contiguous.
// 128x128 tile, BK=64, 256 threads (2x2 waves of 64x64), fp32 MFMA acc.
// m97 structure: global_load_lds width-16 direct to LDS, single-buffered,
// 2 barriers per K-step. LDS rows = 8 chunks of 16B, XOR-swizzled via the
// PRE-SWIZZLED GLOBAL SOURCE: LDS slot s of row holds global chunk s^(row&7);
// reads use the matching XOR (<=2-way banks, free). Measured 903 TF (r1).
// ---------------------------------------------------------------------------
template <bool BIAS, typename TOUT>
__global__ __launch_bounds__(256)
void gemm_bt(const bf16_t* __restrict__ A, const bf16_t* __restrict__ Bw,
             const float* __restrict__ bias, TOUT* __restrict__ C,
             int M, int N, int K) {
  __shared__ __align__(16) char smem[32768];
  char* sA = smem;            // 128 rows x 64 bf16 (128B rows)
  char* sB = smem + 16384;
  const int tid  = threadIdx.x;
  const int lane = tid & 63, wave = tid >> 6;
  const int quad = lane >> 4, l16 = lane & 15;
  const int wm = wave >> 1, wn = wave & 1;
  const int m0 = blockIdx.y * 128, n0 = blockIdx.x * 128;

  f32x4 acc[4][4] = {};
  const int kTiles = K >> 6;

  for (int kt = 0; kt < kTiles; ++kt) {
    const int kb = kt << 6;
#pragma unroll
    for (int i = 0; i < 4; ++i) {
      int p = i * 256 + tid;                 // 1024 chunks of 16B per tile
      int row = p >> 3, gc = (p & 7) ^ (row & 7);
      gl_lds16(A  + (size_t)(m0 + row) * K + kb + gc * 8, sA + p * 16);
      gl_lds16(Bw + (size_t)(n0 + row) * K + kb + gc * 8, sB + p * 16);
    }
    __syncthreads();                         // drains vmcnt -> tile visible

#pragma unroll
    for (int ks = 0; ks < 2; ++ks) {
      bf16x8 af[4], bfr[4];
      const int c = ks * 4 + quad;
#pragma unroll
      for (int i = 0; i < 4; ++i) {
        int ra = wm * 64 + i * 16 + l16;
        af[i]  = *(const bf16x8*)(sA + ra * 128 + ((c ^ (ra & 7)) * 16));
        int rb = wn * 64 + i * 16 + l16;
        bfr[i] = *(const bf16x8*)(sB + rb * 128 + ((c ^ (rb & 7)) * 16));
      }
#pragma unroll
      for (int i = 0; i < 4; ++i)
#pragma unroll
        for (int j = 0; j < 4; ++j)
          acc[i][j] = mfma16(af[i], bfr[j], acc[i][j]);
    }
    __syncthreads();                         // LDS reads done before re-stage
  }
  // epilogue: C/D layout row = quad*4 + r, col = l16 (m89-verified)
#pragma unroll
  for (int i = 0; i < 4; ++i) {
    int mrow = m0 + wm * 64 + i * 16 + quad * 4;
#pragma unroll
    for (int j = 0; j < 4; ++j) {
      int ncol = n0 + wn * 64 + j * 16 + l16;
      float bv = BIAS ? bias[ncol] : 0.f;
#pragma unroll
      for (int r = 0; r < 4; ++r)
        store_val(&C[(size_t)(mrow + r) * N + ncol], acc[i][j][r] + bv);
    }
  }
}

// ---------------------------------------------------------------------------
// postproc: ONE dispatch, three independent block-parallel jobs (all consume
// data already written before this dispatch; no intra-dispatch ordering):
//  blocks [0, 20480): prep — q/k RMSNorm+RoPE. wave = one (t, slot<40) row.
//  blocks [20480, 20992): vtrans — V transpose straight from qkv.
//  blocks [20992, 29184): cvt — wo fp32 -> bf16 (2048 elems/block).
// ---------------------------------------------------------------------------
#define PP_PREP_BLOCKS 20480
#define PP_VT_BLOCKS   512
#define PP_CVT_BLOCKS  8192
__global__ __launch_bounds__(256)
void postproc_kernel(const bf16_t* __restrict__ qkv,
                     const float* __restrict__ qw, const float* __restrict__ kw,
                     const float* __restrict__ wo,
                     bf16_t* __restrict__ Qp, bf16_t* __restrict__ Kp,
                     bf16_t* __restrict__ Vt, bf16_t* __restrict__ wob) {
  __shared__ bf16_t tile[64 * 66];
  const int bid = blockIdx.x;
  const int tid = threadIdx.x;

  if (bid < PP_PREP_BLOCKS) {
    // ---- prep: RMSNorm + RoPE for q (slot<32) and k (slot 32..39) ----
    const int id   = bid * 4 + (tid >> 6);
    const int lane = tid & 63;
    const int t = id / 40, slot = id % 40;
    const bf16_t* src = qkv + (size_t)t * NQKV + slot * DH;
    float x1 = b2f(src[lane]), x2 = b2f(src[lane + 64]);
    float ssq = x1 * x1 + x2 * x2;
#pragma unroll
    for (int m = 1; m < 64; m <<= 1) ssq += __shfl_xor(ssq, m, 64);
    float rms = rsqrtf(ssq * (1.f / 128.f) + 1e-6f);
    const float* w = (slot < 32) ? qw : kw;
    float n1 = x1 * rms * w[lane];
    float n2 = x2 * rms * w[lane + 64];
    float inv = exp2f(-0.20762050593046014f * (float)lane);
    float ang = (float)t * inv;
    float cs = __cosf(ang), sn = __sinf(ang);   // |ang|<=2047: err ~2.5e-4 << bf16 eps
    bf16_t* dst = (slot < 32) ? Qp + ((size_t)t * NH  + slot)        * DH
                              : Kp + ((size_t)t * NKV + (slot - 32)) * DH;
    dst[lane]      = f2b(n1 * cs - n2 * sn);
    dst[lane + 64] = f2b(n2 * cs + n1 * sn);
  } else if (bid < PP_PREP_BLOCKS + PP_VT_BLOCKS) {
    // ---- vtrans: qkv V-slots (t, 40+kvh, d) -> Vt (kvh, d, t) ----
    const int b = bid - PP_PREP_BLOCKS;
    const int t0 = (b & 31) * 64, d0 = ((b >> 5) & 1) * 64, kvh = b >> 6;
#pragma unroll
    for (int i = 0; i < 2; ++i) {
      int id = i * 256 + tid;            // 512 chunks: 64 t-rows x 8 d-chunks
      int tr = id >> 3, dc = id & 7;
      bf16x8 v = *(const bf16x8*)(qkv + (size_t)(t0 + tr) * NQKV +
                                  (40 + kvh) * DH + d0 + dc * 8);
#pragma unroll
      for (int e = 0; e < 8; ++e) tile[tr * 66 + dc * 8 + e] = v[e];
    }
    __syncthreads();
#pragma unroll
    for (int i = 0; i < 2; ++i) {
      int id = i * 256 + tid;            // 64 d-rows x 8 t-chunks
      int dr = id >> 3, tc = id & 7;
      bf16x8 o;
#pragma unroll
      for (int e = 0; e < 8; ++e) o[e] = tile[(tc * 8 + e) * 66 + dr];
      *(bf16x8*)(Vt + ((size_t)kvh * DH + d0 + dr) * T_SEQ + t0 + tc * 8) = o;
    }
  } else {
    // ---- cvt: wo fp32 -> bf16 ----
    const int c = bid - (PP_PREP_BLOCKS + PP_VT_BLOCKS);
    size_t i = ((size_t)c * 256 + tid) * 8;
    f32x4 a = *(const f32x4*)(wo + i);
    f32x4 bq = *(const f32x4*)(wo + i + 4);
    bf16x8 o;
#pragma unroll
    for (int e = 0; e < 4; ++e) { o[e] = f2b(a[e]); o[e + 4] = f2b(bq[e]); }
    *(bf16x8*)(wob + i) = o;
  }
}

// ---------------------------------------------------------------------------
// attn: flash attention. UNPAIRED causal q-tiles: block = (q-tile, head),
// grid (32, 32) = 1024 blocks, qt = 31 - blockIdx.x (longest blocks first).
// K double-buffered in LDS (gl_lds prefetch); V READ DIRECT from Vt (L2/L1
// resident, 4.2MB total; per-instruction access = 16 rows x 64B full lines).
// STATIC-MAX softmax p = exp2(s*C1 - C2); per-lane l partials, one shuffle
// reduction in the epilogue. LDS 40KB (sK x2 + sP 8K) -> 4 blocks/CU,
// 16 waves/CU (was 2 blocks/8 waves; MfmaUtil 11% latency-bound).
// ---------------------------------------------------------------------------
__global__ __launch_bounds__(256)
void attn_kernel(const bf16_t* __restrict__ Qp, const bf16_t* __restrict__ Kp,
                 const bf16_t* __restrict__ Vt, bf16_t* __restrict__ Out) {
  __shared__ __align__(16) char smem[40960];
  // [0,32K): sK parity 0/1 (64 rows x 256B, swizzle c^(row&15))
  // [32K,40K): sP (2KB per wave)
  const int tid  = threadIdx.x;
  const int lane = tid & 63, wave = tid >> 6;
  const int quad = lane >> 4, l16 = lane & 15;
  const int qt = 31 - blockIdx.x, h = blockIdx.y;
  const int kvh = h >> 2;                  // GQA: 4 q-heads per kv-head
  char* sPw = smem + 32768 + wave * 2048;
  const bf16_t* Vbase = Vt + (size_t)kvh * DH * T_SEQ;

  // Q fragments: A-layout row m=l16, k = ks*32 + quad*8 + j. Direct global.
  bf16x8 qf[4];
  {
    const int row = qt * 64 + wave * 16 + l16;
#pragma unroll
    for (int ks = 0; ks < 4; ++ks)
      qf[ks] = *(const bf16x8*)(Qp + ((size_t)row * NH + h) * DH + ks * 32 + quad * 8);
  }
  f32x4 acc[8] = {};
  float lrow[4] = {0.f, 0.f, 0.f, 0.f};

  auto stage = [&](int kt) {
    char* sK = smem + (kt & 1) * 16384;
    const int k0 = kt * 64;
#pragma unroll
    for (int i = 0; i < 4; ++i) {
      int p = i * 256 + tid;                 // K tile: 64 rows x 16 chunks
      int row = p >> 4, gc = (p & 15) ^ (row & 15);
      gl_lds16(Kp + ((size_t)(k0 + row) * NKV + kvh) * DH + gc * 8, sK + p * 16);
    }
  };

  stage(0);
  for (int kt = 0; kt <= qt; ++kt) {
    __syncthreads();                 // drains vmcnt: K tile kt ready
    if (kt < qt) stage(kt + 1);      // prefetch into opposite parity
    char* sK = smem + (kt & 1) * 16384;
    const int k0 = kt * 64;

    // S = Q K^T (wave's 16 rows x 64 keys)
    f32x4 sfr[4] = {};
#pragma unroll
    for (int ks = 0; ks < 4; ++ks) {
      const int c = ks * 4 + quad;
#pragma unroll
      for (int j = 0; j < 4; ++j) {
        int row = j * 16 + l16;
        bf16x8 kf = *(const bf16x8*)(sK + row * 256 + ((c ^ (row & 15)) * 16));
        sfr[j] = mfma16(qf[ks], kf, sfr[j]);
      }
    }
    // p = exp2(s*C1 - C2); masked -> 0. No reductions in the loop.
    float sv[4][4];
    const bool diag = (kt == qt);
#pragma unroll
    for (int j = 0; j < 4; ++j)
#pragma unroll
      for (int r = 0; r < 4; ++r) {
        float e = exp2f(fmaf(sfr[j][r], C1_EXP2, -C2_EXP2));
        if (diag) {
          int qg = wave * 16 + quad * 4 + r;
          int kg = j * 16 + l16;
          if (kg > qg) e = 0.f;
        }
        sv[j][r] = e;
      }
#pragma unroll
    for (int r = 0; r < 4; ++r)
      lrow[r] += (sv[0][r] + sv[1][r]) + (sv[2][r] + sv[3][r]);
    // P -> per-wave LDS (C-layout write, A-layout read), swizzled
#pragma unroll
    for (int j = 0; j < 4; ++j)
#pragma unroll
      for (int r = 0; r < 4; ++r) {
        int prow = quad * 4 + r;
        int col  = j * 16 + l16;
        int c    = col >> 3;
        ((bf16_t*)(sPw + prow * 128 + ((c ^ (prow & 7)) * 16)))[col & 7] = f2b(sv[j][r]);
      }
    __asm__ volatile("" ::: "memory");   // keep ds_reads below the ds_writes
    bf16x8 pf[2];
#pragma unroll
    for (int ks2 = 0; ks2 < 2; ++ks2) {
      int c = ks2 * 4 + quad;
      pf[ks2] = *(const bf16x8*)(sPw + l16 * 128 + ((c ^ (l16 & 7)) * 16));
    }
    __asm__ volatile("" ::: "memory");   // next iter's P-writes stay below
    // O += P V  (V direct from global: lane reads 16B of keys for its d;
    // quads contiguous -> 16 rows x 64B full cache lines per instruction)
#pragma unroll
    for (int j2 = 0; j2 < 8; ++j2) {
      int d = j2 * 16 + l16;
      const bf16_t* vrow = Vbase + (size_t)d * T_SEQ + k0;
#pragma unroll
      for (int ks2 = 0; ks2 < 2; ++ks2) {
        int c = ks2 * 4 + quad;
        bf16x8 vf = *(const bf16x8*)(vrow + c * 8);
        acc[j2] = mfma16(pf[ks2], vf, acc[j2]);
      }
    }
  }

  // epilogue: reduce per-lane l partials over the 16-lane quad group,
  // divide, write (T, NH*DH)
#pragma unroll
  for (int r = 0; r < 4; ++r) {
    float lv = lrow[r];
#pragma unroll
    for (int m = 1; m < 16; m <<= 1) lv += __shfl_xor(lv, m, 64);
    float inv = 1.f / lv;
    int qg = qt * 64 + wave * 16 + quad * 4 + r;
#pragma unroll
    for (int j2 = 0; j2 < 8; ++j2) {
      int d = j2 * 16 + l16;
      Out[(size_t)qg * (NH * DH) + h * DH + d] = f2b(acc[j2][r] * inv);
    }
  }
}

// ---------------------------------------------------------------------------
extern "C" void kernel_launch(void* const* d_in, const int* in_sizes, int n_in,
                              void* d_out, int out_size, void* d_ws, size_t ws_size,
                              hipStream_t stream) {
  const float* x    = (const float*)d_in[0];   // (2048, 4096)
  const float* wqkv = (const float*)d_in[1];   // (6144, 4096)
  const float* bqkv = (const float*)d_in[2];   // (6144,)
  const float* qnw  = (const float*)d_in[3];   // (128,)
  const float* knw  = (const float*)d_in[4];   // (128,)
  const float* wo   = (const float*)d_in[5];   // (4096, 4096)
  float* out = (float*)d_out;                  // (2048, 4096) fp32

  // Workspace layout (total 92,274,688 B). Lifetimes:
  //   wqkvb [0, 50.3M)     cvt2 -> gemm1
  //   xb    [50.3M, 67.1M) cvt2 -> gemm1
  //   qkv   [67.1M, 92.3M) gemm1 -> postproc; At aliases here after postproc
  //   after gemm1, [0, 67.1M) is dead and reused by postproc outputs:
  //   Qp 0 (16.8M) | Kp 16.8M | Vt 21.0M | wob 25.2M (33.5M, ends 58.7M)
  char* ws = (char*)d_ws;
  bf16_t* wqkvb = (bf16_t*)(ws);
  bf16_t* xb    = (bf16_t*)(ws + 50331648);
  bf16_t* qkv   = (bf16_t*)(ws + 67108864);
  bf16_t* Qp    = (bf16_t*)(ws);
  bf16_t* Kp    = (bf16_t*)(ws + 16777216);
  bf16_t* Vt    = (bf16_t*)(ws + 20971520);
  bf16_t* wob   = (bf16_t*)(ws + 25165824);
  bf16_t* At    = (bf16_t*)(ws + 67108864);    // aliases qkv (dead after postproc)

  // x: 8.4M elems -> 4096 blocks; wqkv: 25.2M elems -> 12288 blocks
  cvt2_kernel<<<16384, 256, 0, stream>>>(x, xb, 4096, wqkv, wqkvb);
  gemm_bt<true, bf16_t><<<dim3(NQKV / 128, T_SEQ / 128), 256, 0, stream>>>(
      xb, wqkvb, bqkv, qkv, T_SEQ, NQKV, HIDN);
  postproc_kernel<<<PP_PREP_BLOCKS + PP_VT_BLOCKS + PP_CVT_BLOCKS, 256, 0, stream>>>(
      qkv, qnw, knw, wo, Qp, Kp, Vt, wob);
  attn_kernel<<<dim3(32, NH), 256, 0, stream>>>(Qp, Kp, Vt, At);
  gemm_bt<false, float><<<dim3(HIDN / 128, T_SEQ / 128), 256, 0, stream>>>(
      At, wob, nullptr, out, T_SEQ, HIDN, HIDN);
}

// Round 8
// 525.983 us; speedup vs baseline: 1.2979x; 1.2979x over previous
//
#include <hip/hip_runtime.h>
#include <stdint.h>
#include <stddef.h>

// ABI: all inputs fp32, output fp32. fp32 inputs pre-converted ONCE to bf16;
// both GEMMs run the proven global_load_lds-direct bf16 pipeline (m97
// structure, ~900 TF tier). 5 dispatches:
//   cvt2(x,wqkv) -> gemm1 -> postproc(prep + vtrans + wo-cvt) -> attn -> gemm2
// attn this round: KVBLK=32, UNPAIRED q-tiles, grid 1024 = 4 blocks/CU all
// co-resident (LDS 36KB, ~96 VGPR -> 16 waves/CU; was 8). V stays LDS-staged
// (r7 lesson: direct-V global reads put L2 latency in the dependent chain).
typedef __bf16 bf16_t;
typedef __bf16 bf16x8 __attribute__((ext_vector_type(8)));
typedef float  f32x4  __attribute__((ext_vector_type(4)));

#define T_SEQ 2048
#define NH    32
#define NKV   8
#define DH    128
#define HIDN  4096
#define NQKV  6144
#define SCALE 0.08838834764831845f
// Static softmax max-bound: RMSNorm(w=1) + RoPE give ||q||=||k||=sqrt(128)
// (up to bf16 eps), so s*SCALE <= 11.36 < 11.5. Constant shift cancels in
// p/sum(p); removes running-max/rescale entirely.
// exp2 folding: p = exp2(s*SCALE*log2e - MBOUND*log2e)
#define C1_EXP2 0.12751743187767f
#define C2_EXP2 16.590992970223f

__device__ inline float b2f(bf16_t v) {
  uint32_t u = ((uint32_t)__builtin_bit_cast(uint16_t, v)) << 16;
  return __builtin_bit_cast(float, u);
}
__device__ inline bf16_t f2b(float f) { return (bf16_t)f; }  // native RNE cvt
__device__ inline void gl_lds16(const void* g, void* l) {
  __builtin_amdgcn_global_load_lds(
      (__attribute__((address_space(1))) void*)g,
      (__attribute__((address_space(3))) void*)l, 16, 0, 0);
}
__device__ inline f32x4 mfma16(bf16x8 a, bf16x8 b, f32x4 c) {
  return __builtin_amdgcn_mfma_f32_16x16x32_bf16(a, b, c, 0, 0, 0);
}
__device__ inline void store_val(float* p, float v)  { *p = v; }
__device__ inline void store_val(bf16_t* p, float v) { *p = f2b(v); }

// ---------------------------------------------------------------------------
// cvt2: fp32 -> bf16 for two tensors in one dispatch (blocks [0,na) -> a,
// rest -> b). 8 elems/thread (32B load, 16B store).
// ---------------------------------------------------------------------------
__global__ __launch_bounds__(256)
void cvt2_kernel(const float* __restrict__ a, bf16_t* __restrict__ ao, int na,
                 const float* __restrict__ b, bf16_t* __restrict__ bo) {
  int blk = blockIdx.x;
  const float* in;
  bf16_t* out;
  int rb;
  if (blk < na) { in = a; out = ao; rb = blk; }
  else          { in = b; out = bo; rb = blk - na; }
  size_t i = ((size_t)rb * 256 + threadIdx.x) * 8;
  f32x4 va = *(const f32x4*)(in + i);
  f32x4 vb = *(const f32x4*)(in + i + 4);
  bf16x8 o;
#pragma unroll
  for (int e = 0; e < 4; ++e) { o[e] = f2b(va[e]); o[e + 4] = f2b(vb[e]); }
  *(bf16x8*)(out + i) = o;
}

// ---------------------------------------------------------------------------
// GEMM: C[M,N] = A[M,K] * Bw[N,K]^T (+ bias[N]).  A,Bw bf16 K-contiguous.
// 128x128 tile, BK=64, 256 threads (2x2 waves of 64x64), fp32 MFMA acc.
// m97 structure: global_load_lds width-16 direct to LDS, single-buffered,
// 2 barriers per K-step. LDS rows = 8 chunks of 16B, XOR-swizzled via the
// PRE-SWIZZLED GLOBAL SOURCE: LDS slot s of row holds global chunk s^(row&7);
// reads use the matching XOR (<=2-way banks, free). Measured 903 TF (r1).
// ---------------------------------------------------------------------------
template <bool BIAS, typename TOUT>
__global__ __launch_bounds__(256)
void gemm_bt(const bf16_t* __restrict__ A, const bf16_t* __restrict__ Bw,
             const float* __restrict__ bias, TOUT* __restrict__ C,
             int M, int N, int K) {
  __shared__ __align__(16) char smem[32768];
  char* sA = smem;            // 128 rows x 64 bf16 (128B rows)
  char* sB = smem + 16384;
  const int tid  = threadIdx.x;
  const int lane = tid & 63, wave = tid >> 6;
  const int quad = lane >> 4, l16 = lane & 15;
  const int wm = wave >> 1, wn = wave & 1;
  const int m0 = blockIdx.y * 128, n0 = blockIdx.x * 128;

  f32x4 acc[4][4] = {};
  const int kTiles = K >> 6;

  for (int kt = 0; kt < kTiles; ++kt) {
    const int kb = kt << 6;
#pragma unroll
    for (int i = 0; i < 4; ++i) {
      int p = i * 256 + tid;                 // 1024 chunks of 16B per tile
      int row = p >> 3, gc = (p & 7) ^ (row & 7);
      gl_lds16(A  + (size_t)(m0 + row) * K + kb + gc * 8, sA + p * 16);
      gl_lds16(Bw + (size_t)(n0 + row) * K + kb + gc * 8, sB + p * 16);
    }
    __syncthreads();                         // drains vmcnt -> tile visible

#pragma unroll
    for (int ks = 0; ks < 2; ++ks) {
      bf16x8 af[4], bfr[4];
      const int c = ks * 4 + quad;
#pragma unroll
      for (int i = 0; i < 4; ++i) {
        int ra = wm * 64 + i * 16 + l16;
        af[i]  = *(const bf16x8*)(sA + ra * 128 + ((c ^ (ra & 7)) * 16));
        int rb = wn * 64 + i * 16 + l16;
        bfr[i] = *(const bf16x8*)(sB + rb * 128 + ((c ^ (rb & 7)) * 16));
      }
#pragma unroll
      for (int i = 0; i < 4; ++i)
#pragma unroll
        for (int j = 0; j < 4; ++j)
          acc[i][j] = mfma16(af[i], bfr[j], acc[i][j]);
    }
    __syncthreads();                         // LDS reads done before re-stage
  }
  // epilogue: C/D layout row = quad*4 + r, col = l16 (m89-verified)
#pragma unroll
  for (int i = 0; i < 4; ++i) {
    int mrow = m0 + wm * 64 + i * 16 + quad * 4;
#pragma unroll
    for (int j = 0; j < 4; ++j) {
      int ncol = n0 + wn * 64 + j * 16 + l16;
      float bv = BIAS ? bias[ncol] : 0.f;
#pragma unroll
      for (int r = 0; r < 4; ++r)
        store_val(&C[(size_t)(mrow + r) * N + ncol], acc[i][j][r] + bv);
    }
  }
}

// ---------------------------------------------------------------------------
// postproc: ONE dispatch, three independent block-parallel jobs (all consume
// data already written before this dispatch; no intra-dispatch ordering):
//  blocks [0, 20480): prep — q/k RMSNorm+RoPE. wave = one (t, slot<40) row.
//  blocks [20480, 20992): vtrans — V transpose straight from qkv.
//  blocks [20992, 29184): cvt — wo fp32 -> bf16 (2048 elems/block).
// ---------------------------------------------------------------------------
#define PP_PREP_BLOCKS 20480
#define PP_VT_BLOCKS   512
#define PP_CVT_BLOCKS  8192
__global__ __launch_bounds__(256)
void postproc_kernel(const bf16_t* __restrict__ qkv,
                     const float* __restrict__ qw, const float* __restrict__ kw,
                     const float* __restrict__ wo,
                     bf16_t* __restrict__ Qp, bf16_t* __restrict__ Kp,
                     bf16_t* __restrict__ Vt, bf16_t* __restrict__ wob) {
  __shared__ bf16_t tile[64 * 66];
  const int bid = blockIdx.x;
  const int tid = threadIdx.x;

  if (bid < PP_PREP_BLOCKS) {
    // ---- prep: RMSNorm + RoPE for q (slot<32) and k (slot 32..39) ----
    const int id   = bid * 4 + (tid >> 6);
    const int lane = tid & 63;
    const int t = id / 40, slot = id % 40;
    const bf16_t* src = qkv + (size_t)t * NQKV + slot * DH;
    float x1 = b2f(src[lane]), x2 = b2f(src[lane + 64]);
    float ssq = x1 * x1 + x2 * x2;
#pragma unroll
    for (int m = 1; m < 64; m <<= 1) ssq += __shfl_xor(ssq, m, 64);
    float rms = rsqrtf(ssq * (1.f / 128.f) + 1e-6f);
    const float* w = (slot < 32) ? qw : kw;
    float n1 = x1 * rms * w[lane];
    float n2 = x2 * rms * w[lane + 64];
    float inv = exp2f(-0.20762050593046014f * (float)lane);
    float ang = (float)t * inv;
    float cs = __cosf(ang), sn = __sinf(ang);   // |ang|<=2047: err ~2.5e-4 << bf16 eps
    bf16_t* dst = (slot < 32) ? Qp + ((size_t)t * NH  + slot)        * DH
                              : Kp + ((size_t)t * NKV + (slot - 32)) * DH;
    dst[lane]      = f2b(n1 * cs - n2 * sn);
    dst[lane + 64] = f2b(n2 * cs + n1 * sn);
  } else if (bid < PP_PREP_BLOCKS + PP_VT_BLOCKS) {
    // ---- vtrans: qkv V-slots (t, 40+kvh, d) -> Vt (kvh, d, t) ----
    const int b = bid - PP_PREP_BLOCKS;
    const int t0 = (b & 31) * 64, d0 = ((b >> 5) & 1) * 64, kvh = b >> 6;
#pragma unroll
    for (int i = 0; i < 2; ++i) {
      int id = i * 256 + tid;            // 512 chunks: 64 t-rows x 8 d-chunks
      int tr = id >> 3, dc = id & 7;
      bf16x8 v = *(const bf16x8*)(qkv + (size_t)(t0 + tr) * NQKV +
                                  (40 + kvh) * DH + d0 + dc * 8);
#pragma unroll
      for (int e = 0; e < 8; ++e) tile[tr * 66 + dc * 8 + e] = v[e];
    }
    __syncthreads();
#pragma unroll
    for (int i = 0; i < 2; ++i) {
      int id = i * 256 + tid;            // 64 d-rows x 8 t-chunks
      int dr = id >> 3, tc = id & 7;
      bf16x8 o;
#pragma unroll
      for (int e = 0; e < 8; ++e) o[e] = tile[(tc * 8 + e) * 66 + dr];
      *(bf16x8*)(Vt + ((size_t)kvh * DH + d0 + dr) * T_SEQ + t0 + tc * 8) = o;
    }
  } else {
    // ---- cvt: wo fp32 -> bf16 ----
    const int c = bid - (PP_PREP_BLOCKS + PP_VT_BLOCKS);
    size_t i = ((size_t)c * 256 + tid) * 8;
    f32x4 a = *(const f32x4*)(wo + i);
    f32x4 bq = *(const f32x4*)(wo + i + 4);
    bf16x8 o;
#pragma unroll
    for (int e = 0; e < 4; ++e) { o[e] = f2b(a[e]); o[e + 4] = f2b(bq[e]); }
    *(bf16x8*)(wob + i) = o;
  }
}

// ---------------------------------------------------------------------------
// attn: flash attention. KVBLK=32, UNPAIRED q-tiles: block = (slot, head),
// qt = (bx + by) & 31 (bijective per head; any contiguous dispatch window is
// qt-balanced). Grid (32,32) = 1024 blocks = EXACTLY 4/CU, all co-resident
// -> causal imbalance amortized by overlap, no tail pathology.
// K and V both LDS-staged (gl_lds prefetch, double-buffered, pre-swizzled
// sources). STATIC-MAX softmax p = exp2(s*C1 - C2); per-lane l partials,
// one shuffle reduction at the end. LDS 36KB (sK 2x8K + sV 2x8K + sP 4K),
// ~96 VGPR -> 16 waves/CU (was 8: LDS 72K + VGPR 132 double-capped).
// Swizzles (b128-optimal 8 accesses/bank): K slot = c^(row&15) on 256B rows;
// V slot = c^((d>>1)&3) on 64B rows; P slot = c^((prow>>1)&3) on 64B rows.
// ---------------------------------------------------------------------------
__global__ __launch_bounds__(256)
void attn_kernel(const bf16_t* __restrict__ Qp, const bf16_t* __restrict__ Kp,
                 const bf16_t* __restrict__ Vt, bf16_t* __restrict__ Out) {
  __shared__ __align__(16) char smem[36864];
  // [0,16K): sK parity 0/1 (32 rows x 256B)
  // [16K,32K): sV parity 0/1 (128 d-rows x 64B)
  // [32K,36K): sP (1KB per wave: 16 rows x 64B)
  const int tid  = threadIdx.x;
  const int lane = tid & 63, wave = tid >> 6;
  const int quad = lane >> 4, l16 = lane & 15;
  const int qt = (int)((blockIdx.x + blockIdx.y) & 31), h = blockIdx.y;
  const int kvh = h >> 2;                  // GQA: 4 q-heads per kv-head
  char* sPw = smem + 32768 + wave * 1024;

  // Q fragments: A-layout row m=l16, k = ks*32 + quad*8 + j. Direct global.
  bf16x8 qf[4];
  {
    const int row = qt * 64 + wave * 16 + l16;
#pragma unroll
    for (int ks = 0; ks < 4; ++ks)
      qf[ks] = *(const bf16x8*)(Qp + ((size_t)row * NH + h) * DH + ks * 32 + quad * 8);
  }
  f32x4 acc[8] = {};
  float lrow[4] = {0.f, 0.f, 0.f, 0.f};

  auto stage = [&](int kt) {
    char* sK = smem + (kt & 1) * 8192;
    char* sV = smem + 16384 + (kt & 1) * 8192;
    const int k0 = kt * 32;
#pragma unroll
    for (int i = 0; i < 2; ++i) {
      int p = i * 256 + tid;                 // K tile: 32 rows x 16 chunks
      int row = p >> 4, gc = (p & 15) ^ (row & 15);
      gl_lds16(Kp + ((size_t)(k0 + row) * NKV + kvh) * DH + gc * 8, sK + p * 16);
    }
#pragma unroll
    for (int i = 0; i < 2; ++i) {
      int p = i * 256 + tid;                 // V tile: 128 d-rows x 4 chunks
      int d = p >> 2, gc = (p & 3) ^ ((d >> 1) & 3);
      gl_lds16(Vt + ((size_t)kvh * DH + d) * T_SEQ + k0 + gc * 8, sV + p * 16);
    }
  };

  const int ktEnd = 2 * qt + 1;
  stage(0);
  for (int kt = 0; kt <= ktEnd; ++kt) {
    __syncthreads();                 // drains vmcnt: tile kt ready
    if (kt < ktEnd) stage(kt + 1);   // prefetch into opposite parity
    char* sK = smem + (kt & 1) * 8192;
    char* sV = smem + 16384 + (kt & 1) * 8192;

    // S = Q K^T (wave's 16 rows x 32 keys)
    f32x4 sfr[2] = {};
#pragma unroll
    for (int ks = 0; ks < 4; ++ks) {
      const int c = ks * 4 + quad;
#pragma unroll
      for (int j = 0; j < 2; ++j) {
        int row = j * 16 + l16;
        bf16x8 kf = *(const bf16x8*)(sK + row * 256 + ((c ^ (row & 15)) * 16));
        sfr[j] = mfma16(qf[ks], kf, sfr[j]);
      }
    }
    // p = exp2(s*C1 - C2); masked -> 0. No reductions in the loop.
    float sv[2][4];
    const bool diag = (kt >= 2 * qt);        // last two k-tiles touch diagonal
#pragma unroll
    for (int j = 0; j < 2; ++j)
#pragma unroll
      for (int r = 0; r < 4; ++r) {
        float e = exp2f(fmaf(sfr[j][r], C1_EXP2, -C2_EXP2));
        if (diag) {
          int qg = qt * 64 + wave * 16 + quad * 4 + r;
          int kg = kt * 32 + j * 16 + l16;
          if (kg > qg) e = 0.f;
        }
        sv[j][r] = e;
      }
#pragma unroll
    for (int r = 0; r < 4; ++r)
      lrow[r] += sv[0][r] + sv[1][r];
    // P (16x32) -> per-wave LDS (C-layout write, A-layout read), swizzled
#pragma unroll
    for (int j = 0; j < 2; ++j)
#pragma unroll
      for (int r = 0; r < 4; ++r) {
        int prow = quad * 4 + r;
        int col  = j * 16 + l16;
        int slot = (col >> 3) ^ ((prow >> 1) & 3);
        ((bf16_t*)(sPw + prow * 64 + slot * 16))[col & 7] = f2b(sv[j][r]);
      }
    __asm__ volatile("" ::: "memory");   // keep ds_reads below the ds_writes
    bf16x8 pf = *(const bf16x8*)(sPw + l16 * 64 + ((quad ^ ((l16 >> 1) & 3)) * 16));
    __asm__ volatile("" ::: "memory");   // next iter's P-writes stay below
    // O += P V (single K=32 MFMA per d-fragment)
#pragma unroll
    for (int j2 = 0; j2 < 8; ++j2) {
      int d = j2 * 16 + l16;
      bf16x8 vf = *(const bf16x8*)(sV + d * 64 + ((quad ^ ((d >> 1) & 3)) * 16));
      acc[j2] = mfma16(pf, vf, acc[j2]);
    }
  }

  // epilogue: reduce per-lane l partials over the 16-lane quad group,
  // divide, write (T, NH*DH)
#pragma unroll
  for (int r = 0; r < 4; ++r) {
    float lv = lrow[r];
#pragma unroll
    for (int m = 1; m < 16; m <<= 1) lv += __shfl_xor(lv, m, 64);
    float inv = 1.f / lv;
    int qg = qt * 64 + wave * 16 + quad * 4 + r;
#pragma unroll
    for (int j2 = 0; j2 < 8; ++j2) {
      int d = j2 * 16 + l16;
      Out[(size_t)qg * (NH * DH) + h * DH + d] = f2b(acc[j2][r] * inv);
    }
  }
}

// ---------------------------------------------------------------------------
extern "C" void kernel_launch(void* const* d_in, const int* in_sizes, int n_in,
                              void* d_out, int out_size, void* d_ws, size_t ws_size,
                              hipStream_t stream) {
  const float* x    = (const float*)d_in[0];   // (2048, 4096)
  const float* wqkv = (const float*)d_in[1];   // (6144, 4096)
  const float* bqkv = (const float*)d_in[2];   // (6144,)
  const float* qnw  = (const float*)d_in[3];   // (128,)
  const float* knw  = (const float*)d_in[4];   // (128,)
  const float* wo   = (const float*)d_in[5];   // (4096, 4096)
  float* out = (float*)d_out;                  // (2048, 4096) fp32

  // Workspace layout (total 92,274,688 B). Lifetimes:
  //   wqkvb [0, 50.3M)     cvt2 -> gemm1
  //   xb    [50.3M, 67.1M) cvt2 -> gemm1
  //   qkv   [67.1M, 92.3M) gemm1 -> postproc; At aliases here after postproc
  //   after gemm1, [0, 67.1M) is dead and reused by postproc outputs:
  //   Qp 0 (16.8M) | Kp 16.8M | Vt 21.0M | wob 25.2M (33.5M, ends 58.7M)
  char* ws = (char*)d_ws;
  bf16_t* wqkvb = (bf16_t*)(ws);
  bf16_t* xb    = (bf16_t*)(ws + 50331648);
  bf16_t* qkv   = (bf16_t*)(ws + 67108864);
  bf16_t* Qp    = (bf16_t*)(ws);
  bf16_t* Kp    = (bf16_t*)(ws + 16777216);
  bf16_t* Vt    = (bf16_t*)(ws + 20971520);
  bf16_t* wob   = (bf16_t*)(ws + 25165824);
  bf16_t* At    = (bf16_t*)(ws + 67108864);    // aliases qkv (dead after postproc)

  // x: 8.4M elems -> 4096 blocks; wqkv: 25.2M elems -> 12288 blocks
  cvt2_kernel<<<16384, 256, 0, stream>>>(x, xb, 4096, wqkv, wqkvb);
  gemm_bt<true, bf16_t><<<dim3(NQKV / 128, T_SEQ / 128), 256, 0, stream>>>(
      xb, wqkvb, bqkv, qkv, T_SEQ, NQKV, HIDN);
  postproc_kernel<<<PP_PREP_BLOCKS + PP_VT_BLOCKS + PP_CVT_BLOCKS, 256, 0, stream>>>(
      qkv, qnw, knw, wo, Qp, Kp, Vt, wob);
  attn_kernel<<<dim3(32, NH), 256, 0, stream>>>(Qp, Kp, Vt, At);
  gemm_bt<false, float><<<dim3(HIDN / 128, T_SEQ / 128), 256, 0, stream>>>(
      At, wob, nullptr, out, T_SEQ, HIDN, HIDN);
}